// Round 13
// baseline (425.669 us; speedup 1.0000x reference)
//
#include <hip/hip_runtime.h>
#include <cstdint>

#define N_TOK 4096
#define DMODEL 512
#define NHEADS 8
#define HDIM 64

typedef unsigned short u16;
typedef __bf16 bf16x8 __attribute__((ext_vector_type(8)));
typedef float f32x4 __attribute__((ext_vector_type(4)));

union U128 { uint4 u; bf16x8 b; u16 s[8]; };

__device__ __forceinline__ u16 f2bf(float f) {           // RNE
  uint32_t u = __builtin_bit_cast(uint32_t, f);
  u += 0x7FFFu + ((u >> 16) & 1u);
  return (u16)(u >> 16);
}
__device__ __forceinline__ float bf2f(u16 s) {
  uint32_t u = ((uint32_t)s) << 16;
  return __builtin_bit_cast(float, u);
}
__device__ __forceinline__ uint32_t fbit(float f) { return __builtin_bit_cast(uint32_t, f); }

#if __has_builtin(__builtin_amdgcn_exp2f)
#define EXP2(x) __builtin_amdgcn_exp2f(x)
#else
#define EXP2(x) __expf((x) * 0.6931471805599453f)
#endif

// async global->LDS, 16B/lane, dest = wave-uniform base + lane*16
__device__ __forceinline__ void ldg2lds16(const void* g, void* s) {
  __builtin_amdgcn_global_load_lds(
      (const __attribute__((address_space(1))) void*)g,
      (__attribute__((address_space(3))) void*)s, 16, 0, 0);
}

// ---------------------------------------------------------------------------
// Kernel 0: fp32 -> bf16 pre-convert of Q,K,V,WQ,WK,WV,WO.  7168 x 256.
// (r4 lesson: conversion must live OUTSIDE GEMM K-loops.)
// ---------------------------------------------------------------------------
__global__ __launch_bounds__(256) void cvt7_kernel(
    const float* __restrict__ Q, const float* __restrict__ K, const float* __restrict__ V,
    const float* __restrict__ WQ, const float* __restrict__ WK, const float* __restrict__ WV,
    const float* __restrict__ WO,
    u16* __restrict__ Qb, u16* __restrict__ Kb, u16* __restrict__ Vb,
    u16* __restrict__ WQb, u16* __restrict__ WKb, u16* __restrict__ WVb,
    u16* __restrict__ WOb)
{
  int b = blockIdx.x;
  const float* src; u16* dst; int rel;
  if      (b < 2048) { src = Q;  dst = Qb;  rel = b; }
  else if (b < 4096) { src = K;  dst = Kb;  rel = b - 2048; }
  else if (b < 6144) { src = V;  dst = Vb;  rel = b - 4096; }
  else if (b < 6400) { src = WQ; dst = WQb; rel = b - 6144; }
  else if (b < 6656) { src = WK; dst = WKb; rel = b - 6400; }
  else if (b < 6912) { src = WV; dst = WVb; rel = b - 6656; }
  else               { src = WO; dst = WOb; rel = b - 6912; }
  int i = (rel * 256 + threadIdx.x) * 4;
  float4 f = *(const float4*)(src + i);
  ushort4 o;
  o.x = f2bf(f.x); o.y = f2bf(f.y); o.z = f2bf(f.z); o.w = f2bf(f.w);
  *(ushort4*)(dst + i) = o;
}

// ---------------------------------------------------------------------------
// Kernel 1: fused QKV projection, 128x64 tile, m=2, double-buffered LDS,
// pure global_load_lds staging (bf16 in).  V branch writes V^T (Vt[j][n]).
// grid (32, 8, 3), block 256.
// ---------------------------------------------------------------------------
__global__ __launch_bounds__(256) void proj3_kernel(
    const u16* __restrict__ Qb, const u16* __restrict__ Kb, const u16* __restrict__ Vb,
    const u16* __restrict__ WQb, const u16* __restrict__ WKb, const u16* __restrict__ WVb,
    const float* __restrict__ bQ, const float* __restrict__ bK, const float* __restrict__ bV,
    u16* __restrict__ Qs, u16* __restrict__ Ks, u16* __restrict__ Vt)
{
  const int z = blockIdx.z;
  const u16* A      = (z == 0) ? Qb : (z == 1) ? Kb : Vb;
  const u16* W      = (z == 0) ? WQb : (z == 1) ? WKb : WVb;
  const float* bias = (z == 0) ? bQ : (z == 1) ? bK : bV;

  const int m0 = blockIdx.x * 128;
  const int j0 = blockIdx.y * 64;
  const int tid = threadIdx.x;
  const int w = tid >> 6, lane = tid & 63, quad = lane >> 4, l = lane & 15;

  __shared__ bf16x8 sA[2][8][128];  // 32 KB
  __shared__ bf16x8 sB[2][8][64];   // 16 KB

  const f32x4 zero = {0.f, 0.f, 0.f, 0.f};
  f32x4 acc[2][4];
#pragma unroll
  for (int m = 0; m < 2; ++m)
#pragma unroll
    for (int s = 0; s < 4; ++s) acc[m][s] = zero;

  auto stage = [&](int kt, int buf) {
    const int k0 = kt * 64;
#pragma unroll
    for (int i = 0; i < 4; ++i) {
      const int chunk = 2 * w + (i >> 1), half = (i & 1) * 64;
      const u16* ag = A + (size_t)(m0 + half + lane) * DMODEL + k0 + chunk * 8;
      ldg2lds16(ag, (char*)&sA[buf][chunk][half]);
    }
#pragma unroll
    for (int i = 0; i < 2; ++i) {
      const int chunk = 2 * w + i;
      const u16* bg = W + (size_t)(j0 + lane) * DMODEL + k0 + chunk * 8;
      ldg2lds16(bg, (char*)&sB[buf][chunk][0]);
    }
  };

  stage(0, 0);
  __syncthreads();
  for (int kt = 0; kt < 8; ++kt) {
    const int buf = kt & 1;
    if (kt + 1 < 8) stage(kt + 1, buf ^ 1);
#pragma unroll
    for (int c = 0; c < 2; ++c) {
      bf16x8 af0 = sA[buf][c * 4 + quad][w * 32 + l];
      bf16x8 af1 = sA[buf][c * 4 + quad][w * 32 + 16 + l];
#pragma unroll
      for (int s = 0; s < 4; ++s) {
        bf16x8 bfb = sB[buf][c * 4 + quad][s * 16 + l];
        acc[0][s] = __builtin_amdgcn_mfma_f32_16x16x32_bf16(af0, bfb, acc[0][s], 0, 0, 0);
        acc[1][s] = __builtin_amdgcn_mfma_f32_16x16x32_bf16(af1, bfb, acc[1][s], 0, 0, 0);
      }
    }
    __syncthreads();
  }

#pragma unroll
  for (int m = 0; m < 2; ++m)
#pragma unroll
    for (int s = 0; s < 4; ++s) {
      int j = j0 + s * 16 + l;
      float bv = bias[j];
      int n0 = m0 + w * 32 + m * 16 + quad * 4;
      if (z < 2) {
        u16* Y = (z == 0) ? Qs : Ks;
#pragma unroll
        for (int r = 0; r < 4; ++r)
          Y[(size_t)(n0 + r) * DMODEL + j] = f2bf(acc[m][s][r] + bv);
      } else {
        ushort4 pk;
        pk.x = f2bf(acc[m][s][0] + bv); pk.y = f2bf(acc[m][s][1] + bv);
        pk.z = f2bf(acc[m][s][2] + bv); pk.w = f2bf(acc[m][s][3] + bv);
        *(ushort4*)(Vt + (size_t)j * N_TOK + n0) = pk;   // V^T write
      }
    }
}

// ---------------------------------------------------------------------------
// Kernel 2: flash attention (r8/r12 config) + FUSED split-K combine.
// The 4 split-blocks of each (h,qt) arrive at a device-scope atomic counter;
// the last arrival reduces the 4 Opart/Lpart partials and writes ctx.
// No spinning (r10 lesson) — non-last blocks exit immediately.
// All 4 splits share linear_id%8 = h -> partials live in XCD h's L2.
// grid (32 = h+8*split, 16 q-tiles), block 512 = fully co-resident (r11).
// ---------------------------------------------------------------------------
__global__ __launch_bounds__(512, 4) void attn_kernel(
    const u16* __restrict__ Qs, const u16* __restrict__ Ks,
    const u16* __restrict__ Vt, u16* __restrict__ Opart, float* __restrict__ Lpart,
    u16* __restrict__ ctx, unsigned int* __restrict__ cnt)
{
  const int hs = blockIdx.x;                 // h + 8*split
  const int h = hs & 7, split = hs >> 3;
  const int qt = blockIdx.y;
  const int tid = threadIdx.x;
  const int w = tid >> 6, lane = tid & 63, quad = lane >> 4, l = lane & 15;

  __shared__ bf16x8 kch[2][8][64];               // 16 KB  [buf][d-chunk][key]
  __shared__ bf16x8 vch[2][8][64];               // 16 KB  [buf][key-chunk][vd]
  __shared__ __align__(16) u16 pbuf[8][32][40];  // 20 KB  [wave][q][key-half]
  __shared__ int lastflag;

  const int wq0 = qt * 256 + w * 32;

  // Q fragments (B-operand), pre-scaled by log2(e)/8
  bf16x8 qf[2][2];
#pragma unroll
  for (int c = 0; c < 2; ++c)
#pragma unroll
    for (int m = 0; m < 2; ++m) {
      U128 u;
      u.u = *(const uint4*)(Qs + (size_t)(wq0 + m * 16 + l) * DMODEL + h * HDIM + c * 32 + quad * 8);
#pragma unroll
      for (int j = 0; j < 8; ++j) u.s[j] = f2bf(bf2f(u.s[j]) * 0.18033688f);
      qf[c][m] = u.b;
    }

  const f32x4 zero = {0.f, 0.f, 0.f, 0.f};
  f32x4 o[2][4];
  float lsum[2] = {0.f, 0.f};
#pragma unroll
  for (int m = 0; m < 2; ++m)
#pragma unroll
    for (int s = 0; s < 4; ++s) o[m][s] = zero;

  auto stage = [&](int it, int buf) {
    const int j0 = split * 1024 + it * 64;
    if (w < 4) {            // waves 0-3 stage K (8 KB)
      const u16* kg = Ks + (size_t)(j0 + lane) * DMODEL + h * HDIM + w * 16;
      ldg2lds16(kg,     (char*)&kch[buf][2 * w][0]);
      ldg2lds16(kg + 8, (char*)&kch[buf][2 * w + 1][0]);
    } else {                // waves 4-7 stage V^T (8 KB)
      const int w2 = w - 4;
      const u16* vg = Vt + (size_t)(h * HDIM + lane) * N_TOK + j0 + w2 * 16;
      ldg2lds16(vg,     (char*)&vch[buf][2 * w2][0]);
      ldg2lds16(vg + 8, (char*)&vch[buf][2 * w2 + 1][0]);
    }
  };

  stage(0, 0);
  __syncthreads();

  for (int it = 0; it < 16; ++it) {
    const int buf = it & 1;
    if (it + 1 < 16) stage(it + 1, buf ^ 1);   // prefetch overlaps compute

#pragma unroll
    for (int kh = 0; kh < 2; ++kh) {           // two 32-key halves
#pragma unroll
      for (int tt = 0; tt < 2; ++tt) {
        const int t = kh * 2 + tt;
        f32x4 sacc[2];
        sacc[0] = zero; sacc[1] = zero;
#pragma unroll
        for (int c = 0; c < 2; ++c) {
          bf16x8 kf = kch[buf][c * 4 + quad][t * 16 + l];
          sacc[0] = __builtin_amdgcn_mfma_f32_16x16x32_bf16(kf, qf[c][0], sacc[0], 0, 0, 0);
          sacc[1] = __builtin_amdgcn_mfma_f32_16x16x32_bf16(kf, qf[c][1], sacc[1], 0, 0, 0);
        }
#pragma unroll
        for (int m = 0; m < 2; ++m) {
          float p0 = EXP2(sacc[m][0]);
          float p1 = EXP2(sacc[m][1]);
          float p2 = EXP2(sacc[m][2]);
          float p3 = EXP2(sacc[m][3]);
          lsum[m] += (p0 + p1) + (p2 + p3);
          uint2 st;
          st.x = (fbit(p0) >> 16) | (fbit(p1) & 0xFFFF0000u);
          st.y = (fbit(p2) >> 16) | (fbit(p3) & 0xFFFF0000u);
          *(uint2*)&pbuf[w][m * 16 + l][tt * 16 + quad * 4] = st;   // per-wave
        }
      }
      // PV for this key half (contraction = 32 keys, quad covers them)
      U128 pf0, pf1;
      pf0.u = *(const uint4*)&pbuf[w][l][quad * 8];
      pf1.u = *(const uint4*)&pbuf[w][16 + l][quad * 8];
#pragma unroll
      for (int s = 0; s < 4; ++s) {
        bf16x8 vf = vch[buf][kh * 4 + quad][s * 16 + l];
        o[0][s] = __builtin_amdgcn_mfma_f32_16x16x32_bf16(pf0.b, vf, o[0][s], 0, 0, 0);
        o[1][s] = __builtin_amdgcn_mfma_f32_16x16x32_bf16(pf1.b, vf, o[1][s], 0, 0, 0);
      }
    }
    __syncthreads();   // publishes next buf's loads; orders buf reuse
  }

#pragma unroll
  for (int m = 0; m < 2; ++m) {
    lsum[m] += __shfl_xor(lsum[m], 16);
    lsum[m] += __shfl_xor(lsum[m], 32);
  }
  if (quad == 0) {
    Lpart[((size_t)split * NHEADS + h) * N_TOK + wq0 + l]      = lsum[0];
    Lpart[((size_t)split * NHEADS + h) * N_TOK + wq0 + 16 + l] = lsum[1];
  }
  // Opart[split][h][q][vd] bf16 (unnormalized)
  u16* Ob = Opart + ((size_t)(split * NHEADS + h) * N_TOK + wq0) * 64;
#pragma unroll
  for (int m = 0; m < 2; ++m)
#pragma unroll
    for (int s = 0; s < 4; ++s)
#pragma unroll
      for (int r = 0; r < 4; ++r)
        Ob[(size_t)(m * 16 + quad * 4 + r) * 64 + s * 16 + l] = f2bf(o[m][s][r]);

  // -------- fused split-K combine: last of the 4 (h,qt) blocks reduces -----
  __threadfence();                           // publish Opart/Lpart device-wide
  __syncthreads();                           // all waves' stores issued
  if (tid == 0) {
    unsigned int old = atomicAdd(&cnt[h * 16 + qt], 1u);
    lastflag = (old == 3u);
  }
  __syncthreads();
  if (lastflag) {
    __threadfence();                         // acquire: see other splits' data
#pragma unroll
    for (int i = 0; i < 4; ++i) {
      int flat = tid + 512 * i;              // 0..2047 = 256 q x 8 vd-groups
      int q = flat >> 3;
      int vd0 = (flat & 7) * 8;
      int n = qt * 256 + q;
      float acc[8] = {0, 0, 0, 0, 0, 0, 0, 0};
      float ls = 0.f;
#pragma unroll
      for (int s = 0; s < 4; ++s) {
        U128 u;
        u.u = *(const uint4*)(Opart + ((size_t)(s * NHEADS + h) * N_TOK + n) * 64 + vd0);
#pragma unroll
        for (int j = 0; j < 8; ++j) acc[j] += bf2f(u.s[j]);
        ls += Lpart[((size_t)s * NHEADS + h) * N_TOK + n];
      }
      float inv = 1.f / ls;
      U128 o8;
#pragma unroll
      for (int j = 0; j < 8; ++j) o8.s[j] = f2bf(acc[j] * inv);
      *(uint4*)(ctx + (size_t)n * DMODEL + h * HDIM + vd0) = o8.u;
    }
  }
}

// ---------------------------------------------------------------------------
// Kernel 3: output projection + bias + residual (64x64 tiles) + FUSED
// LayerNorm: last of the 8 j-tile blocks per 64-row stripe runs LN.
// All 8 share linear_id%8 = mtile%8 -> tmp rows are XCD-local.
// grid (64, 8) = 512 blocks, block 256.
// ---------------------------------------------------------------------------
__global__ __launch_bounds__(256) void gemmo_kernel(
    const u16* __restrict__ ctx, const u16* __restrict__ WOb,
    const float* __restrict__ bO, const float* __restrict__ resid,
    float* __restrict__ Y,
    const float* __restrict__ gamma, const float* __restrict__ beta,
    float* __restrict__ out, unsigned int* __restrict__ cnt2)
{
  const int m0 = blockIdx.x * 64;
  const int j0 = blockIdx.y * 64;
  const int tid = threadIdx.x;
  const int w = tid >> 6, lane = tid & 63, quad = lane >> 4, l = lane & 15;

  __shared__ bf16x8 sA[2][8][64];  // 16 KB
  __shared__ bf16x8 sB[2][8][64];  // 16 KB
  __shared__ int lastf;

  const f32x4 zero = {0.f, 0.f, 0.f, 0.f};
  f32x4 acc[4];
#pragma unroll
  for (int s = 0; s < 4; ++s) acc[s] = zero;

  auto stage = [&](int kt, int buf) {
    const int k0 = kt * 64;
#pragma unroll
    for (int i = 0; i < 2; ++i) {
      const int chunk = 2 * w + i;
      const u16* ag = ctx + (size_t)(m0 + lane) * DMODEL + k0 + chunk * 8;
      ldg2lds16(ag, (char*)&sA[buf][chunk][0]);
      const u16* bg = WOb + (size_t)(j0 + lane) * DMODEL + k0 + chunk * 8;
      ldg2lds16(bg, (char*)&sB[buf][chunk][0]);
    }
  };

  stage(0, 0);
  __syncthreads();
  for (int kt = 0; kt < 8; ++kt) {
    const int buf = kt & 1;
    if (kt + 1 < 8) stage(kt + 1, buf ^ 1);
#pragma unroll
    for (int c = 0; c < 2; ++c) {
      bf16x8 af = sA[buf][c * 4 + quad][w * 16 + l];
#pragma unroll
      for (int s = 0; s < 4; ++s) {
        bf16x8 bfb = sB[buf][c * 4 + quad][s * 16 + l];
        acc[s] = __builtin_amdgcn_mfma_f32_16x16x32_bf16(af, bfb, acc[s], 0, 0, 0);
      }
    }
    __syncthreads();
  }
#pragma unroll
  for (int s = 0; s < 4; ++s) {
    int j = j0 + s * 16 + l;
    float bv = bO[j];
    int n0 = m0 + w * 16 + quad * 4;
#pragma unroll
    for (int r = 0; r < 4; ++r)
      Y[(size_t)(n0 + r) * DMODEL + j] = acc[s][r] + bv + resid[(size_t)(n0 + r) * DMODEL + j];
  }

  // -------- fused LayerNorm: last of the 8 stripe blocks normalizes --------
  __threadfence();
  __syncthreads();
  if (tid == 0) {
    unsigned int old = atomicAdd(&cnt2[blockIdx.x], 1u);
    lastf = (old == 7u);
  }
  __syncthreads();
  if (lastf) {
    __threadfence();
    for (int rr = 0; rr < 16; ++rr) {        // 4 waves x 16 rows = 64 rows
      const int row = m0 + w * 16 + rr;
      const float* x = Y + (size_t)row * DMODEL + lane * 8;
      float4 a = *(const float4*)x;
      float4 b = *(const float4*)(x + 4);

      float s = a.x + a.y + a.z + a.w + b.x + b.y + b.z + b.w;
#pragma unroll
      for (int m = 1; m < 64; m <<= 1) s += __shfl_xor(s, m);
      float mu = s * (1.f / DMODEL);

      float d0 = a.x - mu, d1 = a.y - mu, d2 = a.z - mu, d3 = a.w - mu;
      float d4 = b.x - mu, d5 = b.y - mu, d6 = b.z - mu, d7 = b.w - mu;
      float v = d0*d0 + d1*d1 + d2*d2 + d3*d3 + d4*d4 + d5*d5 + d6*d6 + d7*d7;
#pragma unroll
      for (int m = 1; m < 64; m <<= 1) v += __shfl_xor(v, m);
      float sc = rsqrtf(v * (1.f / DMODEL) + 1e-5f);

      const float* g = gamma + lane * 8;
      const float* be = beta + lane * 8;
      float4 go = *(const float4*)g;
      float4 g1 = *(const float4*)(g + 4);
      float4 bo = *(const float4*)be;
      float4 b1 = *(const float4*)(be + 4);

      float4 y0, y1;
      y0.x = d0 * sc * go.x + bo.x;  y0.y = d1 * sc * go.y + bo.y;
      y0.z = d2 * sc * go.z + bo.z;  y0.w = d3 * sc * go.w + bo.w;
      y1.x = d4 * sc * g1.x + b1.x;  y1.y = d5 * sc * g1.y + b1.y;
      y1.z = d6 * sc * g1.z + b1.z;  y1.w = d7 * sc * g1.w + b1.w;

      float* yp = out + (size_t)row * DMODEL + lane * 8;
      *(float4*)yp = y0;
      *(float4*)(yp + 4) = y1;
    }
  }
}

// ---------------------------------------------------------------------------
extern "C" void kernel_launch(void* const* d_in, const int* in_sizes, int n_in,
                              void* d_out, int out_size, void* d_ws, size_t ws_size,
                              hipStream_t stream)
{
  const float* Q     = (const float*)d_in[0];
  const float* K     = (const float*)d_in[1];
  const float* V     = (const float*)d_in[2];
  const float* WQ    = (const float*)d_in[3];
  const float* bQ    = (const float*)d_in[4];
  const float* WK    = (const float*)d_in[5];
  const float* bK    = (const float*)d_in[6];
  const float* WV    = (const float*)d_in[7];
  const float* bV    = (const float*)d_in[8];
  const float* WO    = (const float*)d_in[9];
  const float* bO    = (const float*)d_in[10];
  const float* gamma = (const float*)d_in[11];
  const float* beta  = (const float*)d_in[12];

  const size_t MB = 1ull << 20;
  char* ws = (char*)d_ws;
  u16* Qb   = (u16*)(ws + 0 * MB);                  // 4 MB each
  u16* Kb   = (u16*)(ws + 4 * MB);
  u16* Vb   = (u16*)(ws + 8 * MB);
  u16* WQb  = (u16*)(ws + 12 * MB);                 // 0.5 MB each
  u16* WKb  = (u16*)(ws + 12 * MB + 512 * 1024);
  u16* WVb  = (u16*)(ws + 13 * MB);
  u16* WOb  = (u16*)(ws + 13 * MB + 512 * 1024);
  u16* Qs   = (u16*)(ws + 14 * MB);                 // 4 MB each
  u16* Ks   = (u16*)(ws + 18 * MB);
  u16* Vt   = (u16*)(ws + 22 * MB);                 // projected V^T [j][n]
  u16* ctx  = (u16*)(ws + 26 * MB);
  u16* Opart = (u16*)(ws + 30 * MB);                // 16 MB bf16 (dead after attn)
  float* tmp = (float*)(ws + 30 * MB);              // 8 MB, overlays Opart
  float* Lpart = (float*)(ws + 46 * MB);            // 0.5 MB
  unsigned int* cnt  = (unsigned int*)(ws + 47 * MB);          // 128 u32 (attn)
  unsigned int* cnt2 = (unsigned int*)(ws + 47 * MB + 4096);   // 64 u32 (gemmo)
  float* out = (float*)d_out;

  hipMemsetAsync(cnt, 0, 8192, stream);   // zero both counters (graph-capturable)
  cvt7_kernel<<<7168, 256, 0, stream>>>(Q, K, V, WQ, WK, WV, WO,
                                        Qb, Kb, Vb, WQb, WKb, WVb, WOb);
  proj3_kernel<<<dim3(32, 8, 3), 256, 0, stream>>>(Qb, Kb, Vb, WQb, WKb, WVb,
                                                   bQ, bK, bV, Qs, Ks, Vt);
  attn_kernel<<<dim3(32, 16), 512, 0, stream>>>(Qs, Ks, Vt, Opart, Lpart, ctx, cnt);
  gemmo_kernel<<<dim3(64, 8), 256, 0, stream>>>(ctx, WOb, bO, Q, tmp,
                                                gamma, beta, out, cnt2);
}

// Round 14
// 200.743 us; speedup vs baseline: 2.1205x; 2.1205x over previous
//
#include <hip/hip_runtime.h>
#include <cstdint>

#define N_TOK 4096
#define DMODEL 512
#define NHEADS 8
#define HDIM 64

typedef unsigned short u16;
typedef __bf16 bf16x8 __attribute__((ext_vector_type(8)));
typedef float f32x4 __attribute__((ext_vector_type(4)));

union U128 { uint4 u; bf16x8 b; u16 s[8]; };

__device__ __forceinline__ u16 f2bf(float f) {           // RNE
  uint32_t u = __builtin_bit_cast(uint32_t, f);
  u += 0x7FFFu + ((u >> 16) & 1u);
  return (u16)(u >> 16);
}
__device__ __forceinline__ float bf2f(u16 s) {
  uint32_t u = ((uint32_t)s) << 16;
  return __builtin_bit_cast(float, u);
}
__device__ __forceinline__ uint32_t fbit(float f) { return __builtin_bit_cast(uint32_t, f); }

#if __has_builtin(__builtin_amdgcn_exp2f)
#define EXP2(x) __builtin_amdgcn_exp2f(x)
#else
#define EXP2(x) __expf((x) * 0.6931471805599453f)
#endif

// async global->LDS, 16B/lane, dest = wave-uniform base + lane*16
__device__ __forceinline__ void ldg2lds16(const void* g, void* s) {
  __builtin_amdgcn_global_load_lds(
      (const __attribute__((address_space(1))) void*)g,
      (__attribute__((address_space(3))) void*)s, 16, 0, 0);
}

// ---------------------------------------------------------------------------
// Kernel 0: fp32 -> bf16 pre-convert of Q,K,V,WQ,WK,WV,WO.  7168 x 256.
// (r4 lesson: conversion must live OUTSIDE GEMM K-loops.)
// ---------------------------------------------------------------------------
__global__ __launch_bounds__(256) void cvt7_kernel(
    const float* __restrict__ Q, const float* __restrict__ K, const float* __restrict__ V,
    const float* __restrict__ WQ, const float* __restrict__ WK, const float* __restrict__ WV,
    const float* __restrict__ WO,
    u16* __restrict__ Qb, u16* __restrict__ Kb, u16* __restrict__ Vb,
    u16* __restrict__ WQb, u16* __restrict__ WKb, u16* __restrict__ WVb,
    u16* __restrict__ WOb)
{
  int b = blockIdx.x;
  const float* src; u16* dst; int rel;
  if      (b < 2048) { src = Q;  dst = Qb;  rel = b; }
  else if (b < 4096) { src = K;  dst = Kb;  rel = b - 2048; }
  else if (b < 6144) { src = V;  dst = Vb;  rel = b - 4096; }
  else if (b < 6400) { src = WQ; dst = WQb; rel = b - 6144; }
  else if (b < 6656) { src = WK; dst = WKb; rel = b - 6400; }
  else if (b < 6912) { src = WV; dst = WVb; rel = b - 6656; }
  else               { src = WO; dst = WOb; rel = b - 6912; }
  int i = (rel * 256 + threadIdx.x) * 4;
  float4 f = *(const float4*)(src + i);
  ushort4 o;
  o.x = f2bf(f.x); o.y = f2bf(f.y); o.z = f2bf(f.z); o.w = f2bf(f.w);
  *(ushort4*)(dst + i) = o;
}

// ---------------------------------------------------------------------------
// Kernel 1: fused QKV projection, 128x64 tile, m=2, double-buffered LDS,
// pure global_load_lds staging (bf16 in).  V branch writes V^T (Vt[j][n]).
// grid (32, 8, 3), block 256.
// ---------------------------------------------------------------------------
__global__ __launch_bounds__(256) void proj3_kernel(
    const u16* __restrict__ Qb, const u16* __restrict__ Kb, const u16* __restrict__ Vb,
    const u16* __restrict__ WQb, const u16* __restrict__ WKb, const u16* __restrict__ WVb,
    const float* __restrict__ bQ, const float* __restrict__ bK, const float* __restrict__ bV,
    u16* __restrict__ Qs, u16* __restrict__ Ks, u16* __restrict__ Vt)
{
  const int z = blockIdx.z;
  const u16* A      = (z == 0) ? Qb : (z == 1) ? Kb : Vb;
  const u16* W      = (z == 0) ? WQb : (z == 1) ? WKb : WVb;
  const float* bias = (z == 0) ? bQ : (z == 1) ? bK : bV;

  const int m0 = blockIdx.x * 128;
  const int j0 = blockIdx.y * 64;
  const int tid = threadIdx.x;
  const int w = tid >> 6, lane = tid & 63, quad = lane >> 4, l = lane & 15;

  __shared__ bf16x8 sA[2][8][128];  // 32 KB
  __shared__ bf16x8 sB[2][8][64];   // 16 KB

  const f32x4 zero = {0.f, 0.f, 0.f, 0.f};
  f32x4 acc[2][4];
#pragma unroll
  for (int m = 0; m < 2; ++m)
#pragma unroll
    for (int s = 0; s < 4; ++s) acc[m][s] = zero;

  auto stage = [&](int kt, int buf) {
    const int k0 = kt * 64;
#pragma unroll
    for (int i = 0; i < 4; ++i) {
      const int chunk = 2 * w + (i >> 1), half = (i & 1) * 64;
      const u16* ag = A + (size_t)(m0 + half + lane) * DMODEL + k0 + chunk * 8;
      ldg2lds16(ag, (char*)&sA[buf][chunk][half]);
    }
#pragma unroll
    for (int i = 0; i < 2; ++i) {
      const int chunk = 2 * w + i;
      const u16* bg = W + (size_t)(j0 + lane) * DMODEL + k0 + chunk * 8;
      ldg2lds16(bg, (char*)&sB[buf][chunk][0]);
    }
  };

  stage(0, 0);
  __syncthreads();
  for (int kt = 0; kt < 8; ++kt) {
    const int buf = kt & 1;
    if (kt + 1 < 8) stage(kt + 1, buf ^ 1);
#pragma unroll
    for (int c = 0; c < 2; ++c) {
      bf16x8 af0 = sA[buf][c * 4 + quad][w * 32 + l];
      bf16x8 af1 = sA[buf][c * 4 + quad][w * 32 + 16 + l];
#pragma unroll
      for (int s = 0; s < 4; ++s) {
        bf16x8 bfb = sB[buf][c * 4 + quad][s * 16 + l];
        acc[0][s] = __builtin_amdgcn_mfma_f32_16x16x32_bf16(af0, bfb, acc[0][s], 0, 0, 0);
        acc[1][s] = __builtin_amdgcn_mfma_f32_16x16x32_bf16(af1, bfb, acc[1][s], 0, 0, 0);
      }
    }
    __syncthreads();
  }

#pragma unroll
  for (int m = 0; m < 2; ++m)
#pragma unroll
    for (int s = 0; s < 4; ++s) {
      int j = j0 + s * 16 + l;
      float bv = bias[j];
      int n0 = m0 + w * 32 + m * 16 + quad * 4;
      if (z < 2) {
        u16* Y = (z == 0) ? Qs : Ks;
#pragma unroll
        for (int r = 0; r < 4; ++r)
          Y[(size_t)(n0 + r) * DMODEL + j] = f2bf(acc[m][s][r] + bv);
      } else {
        ushort4 pk;
        pk.x = f2bf(acc[m][s][0] + bv); pk.y = f2bf(acc[m][s][1] + bv);
        pk.z = f2bf(acc[m][s][2] + bv); pk.w = f2bf(acc[m][s][3] + bv);
        *(ushort4*)(Vt + (size_t)j * N_TOK + n0) = pk;   // V^T write
      }
    }
}

// ---------------------------------------------------------------------------
// Kernel 2: flash attention (r8/r12 config — the verified local optimum).
// S^T = K.Q^T, fixed-max softmax, split-K x4, double-buffered K/V,
// key-half pbuf (52 KB LDS), XCD-locality swizzle, fully co-resident grid
// (32 = h+8*split, 16 q-tiles) = 512 blocks = 2/CU.
// r13 lesson: NO device-scope fences/atomics anywhere in this kernel —
// their presence slowed the main loop 4.7x.
// ---------------------------------------------------------------------------
__global__ __launch_bounds__(512, 4) void attn_kernel(
    const u16* __restrict__ Qs, const u16* __restrict__ Ks,
    const u16* __restrict__ Vt, u16* __restrict__ Opart, float* __restrict__ Lpart)
{
  const int hs = blockIdx.x;                 // h + 8*split
  const int h = hs & 7, split = hs >> 3;
  const int qt = blockIdx.y;
  const int tid = threadIdx.x;
  const int w = tid >> 6, lane = tid & 63, quad = lane >> 4, l = lane & 15;

  __shared__ bf16x8 kch[2][8][64];               // 16 KB  [buf][d-chunk][key]
  __shared__ bf16x8 vch[2][8][64];               // 16 KB  [buf][key-chunk][vd]
  __shared__ __align__(16) u16 pbuf[8][32][40];  // 20 KB  [wave][q][key-half]

  const int wq0 = qt * 256 + w * 32;

  // Q fragments (B-operand), pre-scaled by log2(e)/8
  bf16x8 qf[2][2];
#pragma unroll
  for (int c = 0; c < 2; ++c)
#pragma unroll
    for (int m = 0; m < 2; ++m) {
      U128 u;
      u.u = *(const uint4*)(Qs + (size_t)(wq0 + m * 16 + l) * DMODEL + h * HDIM + c * 32 + quad * 8);
#pragma unroll
      for (int j = 0; j < 8; ++j) u.s[j] = f2bf(bf2f(u.s[j]) * 0.18033688f);
      qf[c][m] = u.b;
    }

  const f32x4 zero = {0.f, 0.f, 0.f, 0.f};
  f32x4 o[2][4];
  float lsum[2] = {0.f, 0.f};
#pragma unroll
  for (int m = 0; m < 2; ++m)
#pragma unroll
    for (int s = 0; s < 4; ++s) o[m][s] = zero;

  auto stage = [&](int it, int buf) {
    const int j0 = split * 1024 + it * 64;
    if (w < 4) {            // waves 0-3 stage K (8 KB)
      const u16* kg = Ks + (size_t)(j0 + lane) * DMODEL + h * HDIM + w * 16;
      ldg2lds16(kg,     (char*)&kch[buf][2 * w][0]);
      ldg2lds16(kg + 8, (char*)&kch[buf][2 * w + 1][0]);
    } else {                // waves 4-7 stage V^T (8 KB)
      const int w2 = w - 4;
      const u16* vg = Vt + (size_t)(h * HDIM + lane) * N_TOK + j0 + w2 * 16;
      ldg2lds16(vg,     (char*)&vch[buf][2 * w2][0]);
      ldg2lds16(vg + 8, (char*)&vch[buf][2 * w2 + 1][0]);
    }
  };

  stage(0, 0);
  __syncthreads();

  for (int it = 0; it < 16; ++it) {
    const int buf = it & 1;
    if (it + 1 < 16) stage(it + 1, buf ^ 1);   // prefetch overlaps compute

#pragma unroll
    for (int kh = 0; kh < 2; ++kh) {           // two 32-key halves
#pragma unroll
      for (int tt = 0; tt < 2; ++tt) {
        const int t = kh * 2 + tt;
        f32x4 sacc[2];
        sacc[0] = zero; sacc[1] = zero;
#pragma unroll
        for (int c = 0; c < 2; ++c) {
          bf16x8 kf = kch[buf][c * 4 + quad][t * 16 + l];
          sacc[0] = __builtin_amdgcn_mfma_f32_16x16x32_bf16(kf, qf[c][0], sacc[0], 0, 0, 0);
          sacc[1] = __builtin_amdgcn_mfma_f32_16x16x32_bf16(kf, qf[c][1], sacc[1], 0, 0, 0);
        }
#pragma unroll
        for (int m = 0; m < 2; ++m) {
          float p0 = EXP2(sacc[m][0]);
          float p1 = EXP2(sacc[m][1]);
          float p2 = EXP2(sacc[m][2]);
          float p3 = EXP2(sacc[m][3]);
          lsum[m] += (p0 + p1) + (p2 + p3);
          uint2 st;
          st.x = (fbit(p0) >> 16) | (fbit(p1) & 0xFFFF0000u);
          st.y = (fbit(p2) >> 16) | (fbit(p3) & 0xFFFF0000u);
          *(uint2*)&pbuf[w][m * 16 + l][tt * 16 + quad * 4] = st;   // per-wave
        }
      }
      // PV for this key half (contraction = 32 keys, quad covers them)
      U128 pf0, pf1;
      pf0.u = *(const uint4*)&pbuf[w][l][quad * 8];
      pf1.u = *(const uint4*)&pbuf[w][16 + l][quad * 8];
#pragma unroll
      for (int s = 0; s < 4; ++s) {
        bf16x8 vf = vch[buf][kh * 4 + quad][s * 16 + l];
        o[0][s] = __builtin_amdgcn_mfma_f32_16x16x32_bf16(pf0.b, vf, o[0][s], 0, 0, 0);
        o[1][s] = __builtin_amdgcn_mfma_f32_16x16x32_bf16(pf1.b, vf, o[1][s], 0, 0, 0);
      }
    }
    __syncthreads();   // publishes next buf's loads; orders buf reuse
  }

#pragma unroll
  for (int m = 0; m < 2; ++m) {
    lsum[m] += __shfl_xor(lsum[m], 16);
    lsum[m] += __shfl_xor(lsum[m], 32);
  }
  if (quad == 0) {
    Lpart[((size_t)split * NHEADS + h) * N_TOK + wq0 + l]      = lsum[0];
    Lpart[((size_t)split * NHEADS + h) * N_TOK + wq0 + 16 + l] = lsum[1];
  }
  // Opart[split][h][q][vd] bf16 (unnormalized)
  u16* Ob = Opart + ((size_t)(split * NHEADS + h) * N_TOK + wq0) * 64;
#pragma unroll
  for (int m = 0; m < 2; ++m)
#pragma unroll
    for (int s = 0; s < 4; ++s)
#pragma unroll
      for (int r = 0; r < 4; ++r)
        Ob[(size_t)(m * 16 + quad * 4 + r) * 64 + s * 16 + l] = f2bf(o[m][s][r]);
}

// ---------------------------------------------------------------------------
// Kernel 3: combine split-K partials (4 splits) -> ctx bf16.  1024 x 256.
// ---------------------------------------------------------------------------
__global__ __launch_bounds__(256) void combine_kernel(
    const u16* __restrict__ Opart, const float* __restrict__ Lpart,
    u16* __restrict__ ctx)
{
  int idx = blockIdx.x * 256 + threadIdx.x;
  int n = idx >> 6;
  int c8 = idx & 63;
  int h = c8 >> 3;
  int vd0 = (c8 & 7) * 8;

  float acc[8] = {0, 0, 0, 0, 0, 0, 0, 0};
  float lsum = 0.f;
#pragma unroll
  for (int s = 0; s < 4; ++s) {
    U128 u;
    u.u = *(const uint4*)(Opart + ((size_t)(s * NHEADS + h) * N_TOK + n) * 64 + vd0);
#pragma unroll
    for (int j = 0; j < 8; ++j) acc[j] += bf2f(u.s[j]);
    lsum += Lpart[((size_t)s * NHEADS + h) * N_TOK + n];
  }
  float inv = 1.f / lsum;
  U128 u;
#pragma unroll
  for (int j = 0; j < 8; ++j) u.s[j] = f2bf(acc[j] * inv);
  *(uint4*)(ctx + (size_t)n * DMODEL + h * HDIM + vd0) = u.u;
}

// ---------------------------------------------------------------------------
// Kernel 4: output projection + bias + residual + IN-BLOCK LayerNorm.
// Row-complete tile: 16 rows x 512 cols per block -> every output row lives
// in one block, so LN needs only an in-block cross-wave reduction (no
// atomics/fences — r13 lesson).  grid 256 blocks x 256 thr, dbuf staging.
// ---------------------------------------------------------------------------
__global__ __launch_bounds__(256) void gemmo_ln_kernel(
    const u16* __restrict__ ctx, const u16* __restrict__ WOb,
    const float* __restrict__ bO, const float* __restrict__ resid,
    const float* __restrict__ gamma, const float* __restrict__ beta,
    float* __restrict__ out)
{
  const int m0 = blockIdx.x * 16;
  const int tid = threadIdx.x;
  const int w = tid >> 6, lane = tid & 63, quad = lane >> 4, l = lane & 15;

  __shared__ bf16x8 sA[2][8][16];    // [buf][k-chunk][row]   4 KB
  __shared__ bf16x8 sB[2][8][512];   // [buf][k-chunk][j]   128 KB
  __shared__ float redS[4][16], redQ[4][16];   // per-wave row partials

  const f32x4 zero = {0.f, 0.f, 0.f, 0.f};
  f32x4 acc[8];
#pragma unroll
  for (int s = 0; s < 8; ++s) acc[s] = zero;

  auto stage = [&](int kt, int buf) {
    const int k0 = kt * 64;
    if (w == 0) {       // A: 16 rows x 64 cols, lane -> (chunk = g*4+(i>>4), row = i&15)
#pragma unroll
      for (int g = 0; g < 2; ++g) {
        const u16* ag = ctx + (size_t)(m0 + (lane & 15)) * DMODEL + k0 + (g * 4 + (lane >> 4)) * 8;
        ldg2lds16(ag, (char*)&sA[buf][g * 4][0]);
      }
    }
    // B: wave w stages j in [w*128, w*128+128): 2 j-groups x 8 chunks
#pragma unroll
    for (int chunk = 0; chunk < 8; ++chunk)
#pragma unroll
      for (int jg = 0; jg < 2; ++jg) {
        const int j = w * 128 + jg * 64 + lane;
        const u16* bg = WOb + (size_t)j * DMODEL + k0 + chunk * 8;
        ldg2lds16(bg, (char*)&sB[buf][chunk][w * 128 + jg * 64]);
      }
  };

  stage(0, 0);
  __syncthreads();
  for (int kt = 0; kt < 8; ++kt) {
    const int buf = kt & 1;
    if (kt + 1 < 8) stage(kt + 1, buf ^ 1);
#pragma unroll
    for (int c = 0; c < 2; ++c) {
      bf16x8 af = sA[buf][c * 4 + quad][l];
#pragma unroll
      for (int s = 0; s < 8; ++s) {
        bf16x8 bfb = sB[buf][c * 4 + quad][w * 128 + s * 16 + l];
        acc[s] = __builtin_amdgcn_mfma_f32_16x16x32_bf16(af, bfb, acc[s], 0, 0, 0);
      }
    }
    __syncthreads();
  }

  // bias + residual, per-row partial sums over this wave's 128 cols
  float y[8][4];
  float sum[4] = {0, 0, 0, 0}, sq[4] = {0, 0, 0, 0};
#pragma unroll
  for (int s = 0; s < 8; ++s) {
    int j = w * 128 + s * 16 + l;
    float bv = bO[j];
#pragma unroll
    for (int r = 0; r < 4; ++r) {
      int n = m0 + quad * 4 + r;
      float v = acc[s][r] + bv + resid[(size_t)n * DMODEL + j];
      y[s][r] = v;
      sum[r] += v;
      sq[r] += v * v;
    }
  }
#pragma unroll
  for (int r = 0; r < 4; ++r) {
#pragma unroll
    for (int m = 1; m < 16; m <<= 1) {
      sum[r] += __shfl_xor(sum[r], m);
      sq[r]  += __shfl_xor(sq[r], m);
    }
  }
  if (l == 0) {
#pragma unroll
    for (int r = 0; r < 4; ++r) {
      redS[w][quad * 4 + r] = sum[r];
      redQ[w][quad * 4 + r] = sq[r];
    }
  }
  __syncthreads();

#pragma unroll
  for (int r = 0; r < 4; ++r) {
    int row = quad * 4 + r;
    float ts = redS[0][row] + redS[1][row] + redS[2][row] + redS[3][row];
    float tq = redQ[0][row] + redQ[1][row] + redQ[2][row] + redQ[3][row];
    float mu = ts * (1.f / DMODEL);
    float var = tq * (1.f / DMODEL) - mu * mu;
    float sc = rsqrtf(var + 1e-5f);
    int n = m0 + row;
#pragma unroll
    for (int s = 0; s < 8; ++s) {
      int j = w * 128 + s * 16 + l;
      out[(size_t)n * DMODEL + j] = (y[s][r] - mu) * sc * gamma[j] + beta[j];
    }
  }
}

// ---------------------------------------------------------------------------
extern "C" void kernel_launch(void* const* d_in, const int* in_sizes, int n_in,
                              void* d_out, int out_size, void* d_ws, size_t ws_size,
                              hipStream_t stream)
{
  const float* Q     = (const float*)d_in[0];
  const float* K     = (const float*)d_in[1];
  const float* V     = (const float*)d_in[2];
  const float* WQ    = (const float*)d_in[3];
  const float* bQ    = (const float*)d_in[4];
  const float* WK    = (const float*)d_in[5];
  const float* bK    = (const float*)d_in[6];
  const float* WV    = (const float*)d_in[7];
  const float* bV    = (const float*)d_in[8];
  const float* WO    = (const float*)d_in[9];
  const float* bO    = (const float*)d_in[10];
  const float* gamma = (const float*)d_in[11];
  const float* beta  = (const float*)d_in[12];

  const size_t MB = 1ull << 20;
  char* ws = (char*)d_ws;
  u16* Qb   = (u16*)(ws + 0 * MB);                  // 4 MB each
  u16* Kb   = (u16*)(ws + 4 * MB);
  u16* Vb   = (u16*)(ws + 8 * MB);
  u16* WQb  = (u16*)(ws + 12 * MB);                 // 0.5 MB each
  u16* WKb  = (u16*)(ws + 12 * MB + 512 * 1024);
  u16* WVb  = (u16*)(ws + 13 * MB);
  u16* WOb  = (u16*)(ws + 13 * MB + 512 * 1024);
  u16* Qs   = (u16*)(ws + 14 * MB);                 // 4 MB each
  u16* Ks   = (u16*)(ws + 18 * MB);
  u16* Vt   = (u16*)(ws + 22 * MB);                 // projected V^T [j][n]
  u16* ctx  = (u16*)(ws + 26 * MB);
  u16* Opart = (u16*)(ws + 30 * MB);                // 16 MB bf16 (dead after combine)
  float* Lpart = (float*)(ws + 46 * MB);            // 0.5 MB
  float* out = (float*)d_out;

  cvt7_kernel<<<7168, 256, 0, stream>>>(Q, K, V, WQ, WK, WV, WO,
                                        Qb, Kb, Vb, WQb, WKb, WVb, WOb);
  proj3_kernel<<<dim3(32, 8, 3), 256, 0, stream>>>(Qb, Kb, Vb, WQb, WKb, WVb,
                                                   bQ, bK, bV, Qs, Ks, Vt);
  attn_kernel<<<dim3(32, 16), 512, 0, stream>>>(Qs, Ks, Vt, Opart, Lpart);
  combine_kernel<<<1024, 256, 0, stream>>>(Opart, Lpart, ctx);
  gemmo_ln_kernel<<<256, 256, 0, stream>>>(ctx, WOb, bO, Q, gamma, beta, out);
}

// Round 15
// 183.150 us; speedup vs baseline: 2.3242x; 1.0961x over previous
//
#include <hip/hip_runtime.h>
#include <cstdint>

#define N_TOK 4096
#define DMODEL 512
#define NHEADS 8
#define HDIM 64

typedef unsigned short u16;
typedef __bf16 bf16x8 __attribute__((ext_vector_type(8)));
typedef __bf16 bf16x2 __attribute__((ext_vector_type(2)));
typedef float f32x4 __attribute__((ext_vector_type(4)));

union U128 { uint4 u; bf16x8 b; u16 s[8]; };

__device__ __forceinline__ u16 f2bf(float f) {           // RNE
  uint32_t u = __builtin_bit_cast(uint32_t, f);
  u += 0x7FFFu + ((u >> 16) & 1u);
  return (u16)(u >> 16);
}
__device__ __forceinline__ float bf2f(u16 s) {
  uint32_t u = ((uint32_t)s) << 16;
  return __builtin_bit_cast(float, u);
}
__device__ __forceinline__ uint32_t fbit(float f) { return __builtin_bit_cast(uint32_t, f); }

// pack 2 fp32 -> 2 bf16 in one uint32.  gfx950 has v_cvt_pk_bf16_f32;
// fall back to truncation shifts if the builtin is unavailable.
__device__ __forceinline__ uint32_t pk_bf16(float a, float b) {
#if __has_builtin(__builtin_amdgcn_cvt_pk_bf16_f32)
  bf16x2 v = __builtin_amdgcn_cvt_pk_bf16_f32(a, b);
  return __builtin_bit_cast(uint32_t, v);
#else
  return (fbit(a) >> 16) | (fbit(b) & 0xFFFF0000u);
#endif
}

#if __has_builtin(__builtin_amdgcn_exp2f)
#define EXP2(x) __builtin_amdgcn_exp2f(x)
#else
#define EXP2(x) __expf((x) * 0.6931471805599453f)
#endif

// async global->LDS, 16B/lane, dest = wave-uniform base + lane*16
__device__ __forceinline__ void ldg2lds16(const void* g, void* s) {
  __builtin_amdgcn_global_load_lds(
      (const __attribute__((address_space(1))) void*)g,
      (__attribute__((address_space(3))) void*)s, 16, 0, 0);
}

// ---------------------------------------------------------------------------
// Kernel 0: fp32 -> bf16 pre-convert of Q,K,V,WQ,WK,WV,WO.  7168 x 256.
// (r4 lesson: conversion must live OUTSIDE GEMM K-loops.)
// ---------------------------------------------------------------------------
__global__ __launch_bounds__(256) void cvt7_kernel(
    const float* __restrict__ Q, const float* __restrict__ K, const float* __restrict__ V,
    const float* __restrict__ WQ, const float* __restrict__ WK, const float* __restrict__ WV,
    const float* __restrict__ WO,
    u16* __restrict__ Qb, u16* __restrict__ Kb, u16* __restrict__ Vb,
    u16* __restrict__ WQb, u16* __restrict__ WKb, u16* __restrict__ WVb,
    u16* __restrict__ WOb)
{
  int b = blockIdx.x;
  const float* src; u16* dst; int rel;
  if      (b < 2048) { src = Q;  dst = Qb;  rel = b; }
  else if (b < 4096) { src = K;  dst = Kb;  rel = b - 2048; }
  else if (b < 6144) { src = V;  dst = Vb;  rel = b - 4096; }
  else if (b < 6400) { src = WQ; dst = WQb; rel = b - 6144; }
  else if (b < 6656) { src = WK; dst = WKb; rel = b - 6400; }
  else if (b < 6912) { src = WV; dst = WVb; rel = b - 6656; }
  else               { src = WO; dst = WOb; rel = b - 6912; }
  int i = (rel * 256 + threadIdx.x) * 4;
  float4 f = *(const float4*)(src + i);
  ushort4 o;
  o.x = f2bf(f.x); o.y = f2bf(f.y); o.z = f2bf(f.z); o.w = f2bf(f.w);
  *(ushort4*)(dst + i) = o;
}

// ---------------------------------------------------------------------------
// Kernel 1: fused QKV projection, 128x64 tile, m=2, double-buffered LDS,
// pure global_load_lds staging (bf16 in).  V branch writes V^T (Vt[j][n]).
// grid (32, 8, 3), block 256.
// ---------------------------------------------------------------------------
__global__ __launch_bounds__(256) void proj3_kernel(
    const u16* __restrict__ Qb, const u16* __restrict__ Kb, const u16* __restrict__ Vb,
    const u16* __restrict__ WQb, const u16* __restrict__ WKb, const u16* __restrict__ WVb,
    const float* __restrict__ bQ, const float* __restrict__ bK, const float* __restrict__ bV,
    u16* __restrict__ Qs, u16* __restrict__ Ks, u16* __restrict__ Vt)
{
  const int z = blockIdx.z;
  const u16* A      = (z == 0) ? Qb : (z == 1) ? Kb : Vb;
  const u16* W      = (z == 0) ? WQb : (z == 1) ? WKb : WVb;
  const float* bias = (z == 0) ? bQ : (z == 1) ? bK : bV;

  const int m0 = blockIdx.x * 128;
  const int j0 = blockIdx.y * 64;
  const int tid = threadIdx.x;
  const int w = tid >> 6, lane = tid & 63, quad = lane >> 4, l = lane & 15;

  __shared__ bf16x8 sA[2][8][128];  // 32 KB
  __shared__ bf16x8 sB[2][8][64];   // 16 KB

  const f32x4 zero = {0.f, 0.f, 0.f, 0.f};
  f32x4 acc[2][4];
#pragma unroll
  for (int m = 0; m < 2; ++m)
#pragma unroll
    for (int s = 0; s < 4; ++s) acc[m][s] = zero;

  auto stage = [&](int kt, int buf) {
    const int k0 = kt * 64;
#pragma unroll
    for (int i = 0; i < 4; ++i) {
      const int chunk = 2 * w + (i >> 1), half = (i & 1) * 64;
      const u16* ag = A + (size_t)(m0 + half + lane) * DMODEL + k0 + chunk * 8;
      ldg2lds16(ag, (char*)&sA[buf][chunk][half]);
    }
#pragma unroll
    for (int i = 0; i < 2; ++i) {
      const int chunk = 2 * w + i;
      const u16* bg = W + (size_t)(j0 + lane) * DMODEL + k0 + chunk * 8;
      ldg2lds16(bg, (char*)&sB[buf][chunk][0]);
    }
  };

  stage(0, 0);
  __syncthreads();
  for (int kt = 0; kt < 8; ++kt) {
    const int buf = kt & 1;
    if (kt + 1 < 8) stage(kt + 1, buf ^ 1);
#pragma unroll
    for (int c = 0; c < 2; ++c) {
      bf16x8 af0 = sA[buf][c * 4 + quad][w * 32 + l];
      bf16x8 af1 = sA[buf][c * 4 + quad][w * 32 + 16 + l];
#pragma unroll
      for (int s = 0; s < 4; ++s) {
        bf16x8 bfb = sB[buf][c * 4 + quad][s * 16 + l];
        acc[0][s] = __builtin_amdgcn_mfma_f32_16x16x32_bf16(af0, bfb, acc[0][s], 0, 0, 0);
        acc[1][s] = __builtin_amdgcn_mfma_f32_16x16x32_bf16(af1, bfb, acc[1][s], 0, 0, 0);
      }
    }
    __syncthreads();
  }

#pragma unroll
  for (int m = 0; m < 2; ++m)
#pragma unroll
    for (int s = 0; s < 4; ++s) {
      int j = j0 + s * 16 + l;
      float bv = bias[j];
      int n0 = m0 + w * 32 + m * 16 + quad * 4;
      if (z < 2) {
        u16* Y = (z == 0) ? Qs : Ks;
#pragma unroll
        for (int r = 0; r < 4; ++r)
          Y[(size_t)(n0 + r) * DMODEL + j] = f2bf(acc[m][s][r] + bv);
      } else {
        ushort4 pk;
        pk.x = f2bf(acc[m][s][0] + bv); pk.y = f2bf(acc[m][s][1] + bv);
        pk.z = f2bf(acc[m][s][2] + bv); pk.w = f2bf(acc[m][s][3] + bv);
        *(ushort4*)(Vt + (size_t)j * N_TOK + n0) = pk;   // V^T write
      }
    }
}

// ---------------------------------------------------------------------------
// Kernel 2: flash attention (r8/r12 config — the verified local optimum).
// S^T = K.Q^T, fixed-max softmax, split-K x4, double-buffered K/V,
// key-half pbuf (52 KB LDS), XCD-locality swizzle, fully co-resident grid
// (32 = h+8*split, 16 q-tiles) = 512 blocks = 2/CU.
// r13 lesson: NO device-scope fences/atomics in this kernel (4.7x slowdown).
// r15: softmax pack via v_cvt_pk_bf16_f32 (guarded) — cuts ~32 VALU ops/iter.
// ---------------------------------------------------------------------------
__global__ __launch_bounds__(512, 4) void attn_kernel(
    const u16* __restrict__ Qs, const u16* __restrict__ Ks,
    const u16* __restrict__ Vt, u16* __restrict__ Opart, float* __restrict__ Lpart)
{
  const int hs = blockIdx.x;                 // h + 8*split
  const int h = hs & 7, split = hs >> 3;
  const int qt = blockIdx.y;
  const int tid = threadIdx.x;
  const int w = tid >> 6, lane = tid & 63, quad = lane >> 4, l = lane & 15;

  __shared__ bf16x8 kch[2][8][64];               // 16 KB  [buf][d-chunk][key]
  __shared__ bf16x8 vch[2][8][64];               // 16 KB  [buf][key-chunk][vd]
  __shared__ __align__(16) u16 pbuf[8][32][40];  // 20 KB  [wave][q][key-half]

  const int wq0 = qt * 256 + w * 32;

  // Q fragments (B-operand), pre-scaled by log2(e)/8
  bf16x8 qf[2][2];
#pragma unroll
  for (int c = 0; c < 2; ++c)
#pragma unroll
    for (int m = 0; m < 2; ++m) {
      U128 u;
      u.u = *(const uint4*)(Qs + (size_t)(wq0 + m * 16 + l) * DMODEL + h * HDIM + c * 32 + quad * 8);
#pragma unroll
      for (int j = 0; j < 8; ++j) u.s[j] = f2bf(bf2f(u.s[j]) * 0.18033688f);
      qf[c][m] = u.b;
    }

  const f32x4 zero = {0.f, 0.f, 0.f, 0.f};
  f32x4 o[2][4];
  float lsum[2] = {0.f, 0.f};
#pragma unroll
  for (int m = 0; m < 2; ++m)
#pragma unroll
    for (int s = 0; s < 4; ++s) o[m][s] = zero;

  auto stage = [&](int it, int buf) {
    const int j0 = split * 1024 + it * 64;
    if (w < 4) {            // waves 0-3 stage K (8 KB)
      const u16* kg = Ks + (size_t)(j0 + lane) * DMODEL + h * HDIM + w * 16;
      ldg2lds16(kg,     (char*)&kch[buf][2 * w][0]);
      ldg2lds16(kg + 8, (char*)&kch[buf][2 * w + 1][0]);
    } else {                // waves 4-7 stage V^T (8 KB)
      const int w2 = w - 4;
      const u16* vg = Vt + (size_t)(h * HDIM + lane) * N_TOK + j0 + w2 * 16;
      ldg2lds16(vg,     (char*)&vch[buf][2 * w2][0]);
      ldg2lds16(vg + 8, (char*)&vch[buf][2 * w2 + 1][0]);
    }
  };

  stage(0, 0);
  __syncthreads();

  for (int it = 0; it < 16; ++it) {
    const int buf = it & 1;
    if (it + 1 < 16) stage(it + 1, buf ^ 1);   // prefetch overlaps compute

#pragma unroll
    for (int kh = 0; kh < 2; ++kh) {           // two 32-key halves
#pragma unroll
      for (int tt = 0; tt < 2; ++tt) {
        const int t = kh * 2 + tt;
        f32x4 sacc[2];
        sacc[0] = zero; sacc[1] = zero;
#pragma unroll
        for (int c = 0; c < 2; ++c) {
          bf16x8 kf = kch[buf][c * 4 + quad][t * 16 + l];
          sacc[0] = __builtin_amdgcn_mfma_f32_16x16x32_bf16(kf, qf[c][0], sacc[0], 0, 0, 0);
          sacc[1] = __builtin_amdgcn_mfma_f32_16x16x32_bf16(kf, qf[c][1], sacc[1], 0, 0, 0);
        }
#pragma unroll
        for (int m = 0; m < 2; ++m) {
          float p0 = EXP2(sacc[m][0]);
          float p1 = EXP2(sacc[m][1]);
          float p2 = EXP2(sacc[m][2]);
          float p3 = EXP2(sacc[m][3]);
          lsum[m] += (p0 + p1) + (p2 + p3);
          uint2 st;
          st.x = pk_bf16(p0, p1);
          st.y = pk_bf16(p2, p3);
          *(uint2*)&pbuf[w][m * 16 + l][tt * 16 + quad * 4] = st;   // per-wave
        }
      }
      // PV for this key half (contraction = 32 keys, quad covers them)
      U128 pf0, pf1;
      pf0.u = *(const uint4*)&pbuf[w][l][quad * 8];
      pf1.u = *(const uint4*)&pbuf[w][16 + l][quad * 8];
#pragma unroll
      for (int s = 0; s < 4; ++s) {
        bf16x8 vf = vch[buf][kh * 4 + quad][s * 16 + l];
        o[0][s] = __builtin_amdgcn_mfma_f32_16x16x32_bf16(pf0.b, vf, o[0][s], 0, 0, 0);
        o[1][s] = __builtin_amdgcn_mfma_f32_16x16x32_bf16(pf1.b, vf, o[1][s], 0, 0, 0);
      }
    }
    __syncthreads();   // publishes next buf's loads; orders buf reuse
  }

#pragma unroll
  for (int m = 0; m < 2; ++m) {
    lsum[m] += __shfl_xor(lsum[m], 16);
    lsum[m] += __shfl_xor(lsum[m], 32);
  }
  if (quad == 0) {
    Lpart[((size_t)split * NHEADS + h) * N_TOK + wq0 + l]      = lsum[0];
    Lpart[((size_t)split * NHEADS + h) * N_TOK + wq0 + 16 + l] = lsum[1];
  }
  // Opart[split][h][q][vd] bf16 (unnormalized)
  u16* Ob = Opart + ((size_t)(split * NHEADS + h) * N_TOK + wq0) * 64;
#pragma unroll
  for (int m = 0; m < 2; ++m)
#pragma unroll
    for (int s = 0; s < 4; ++s)
#pragma unroll
      for (int r = 0; r < 4; ++r)
        Ob[(size_t)(m * 16 + quad * 4 + r) * 64 + s * 16 + l] = f2bf(o[m][s][r]);
}

// ---------------------------------------------------------------------------
// Kernel 3: combine split-K partials (4 splits) -> ctx bf16.  1024 x 256.
// ---------------------------------------------------------------------------
__global__ __launch_bounds__(256) void combine_kernel(
    const u16* __restrict__ Opart, const float* __restrict__ Lpart,
    u16* __restrict__ ctx)
{
  int idx = blockIdx.x * 256 + threadIdx.x;
  int n = idx >> 6;
  int c8 = idx & 63;
  int h = c8 >> 3;
  int vd0 = (c8 & 7) * 8;

  float acc[8] = {0, 0, 0, 0, 0, 0, 0, 0};
  float lsum = 0.f;
#pragma unroll
  for (int s = 0; s < 4; ++s) {
    U128 u;
    u.u = *(const uint4*)(Opart + ((size_t)(s * NHEADS + h) * N_TOK + n) * 64 + vd0);
#pragma unroll
    for (int j = 0; j < 8; ++j) acc[j] += bf2f(u.s[j]);
    lsum += Lpart[((size_t)s * NHEADS + h) * N_TOK + n];
  }
  float inv = 1.f / lsum;
  U128 u;
#pragma unroll
  for (int j = 0; j < 8; ++j) u.s[j] = f2bf(acc[j] * inv);
  *(uint4*)(ctx + (size_t)n * DMODEL + h * HDIM + vd0) = u.u;
}

// ---------------------------------------------------------------------------
// Kernel 4: output projection + bias + residual, 64x64 tile, double-buffered.
// grid (64, 8) = 512 blocks = 2/CU.  (r14 lesson: row-complete LN fusion
// multiplies WO staging traffic 2x and loses — keep LN separate.)
// ---------------------------------------------------------------------------
__global__ __launch_bounds__(256) void gemmo_kernel(
    const u16* __restrict__ ctx, const u16* __restrict__ WOb,
    const float* __restrict__ bO, const float* __restrict__ resid,
    float* __restrict__ Y)
{
  const int m0 = blockIdx.x * 64;
  const int j0 = blockIdx.y * 64;
  const int tid = threadIdx.x;
  const int w = tid >> 6, lane = tid & 63, quad = lane >> 4, l = lane & 15;

  __shared__ bf16x8 sA[2][8][64];  // 16 KB
  __shared__ bf16x8 sB[2][8][64];  // 16 KB

  const f32x4 zero = {0.f, 0.f, 0.f, 0.f};
  f32x4 acc[4];
#pragma unroll
  for (int s = 0; s < 4; ++s) acc[s] = zero;

  auto stage = [&](int kt, int buf) {
    const int k0 = kt * 64;
#pragma unroll
    for (int i = 0; i < 2; ++i) {
      const int chunk = 2 * w + i;
      const u16* ag = ctx + (size_t)(m0 + lane) * DMODEL + k0 + chunk * 8;
      ldg2lds16(ag, (char*)&sA[buf][chunk][0]);
      const u16* bg = WOb + (size_t)(j0 + lane) * DMODEL + k0 + chunk * 8;
      ldg2lds16(bg, (char*)&sB[buf][chunk][0]);
    }
  };

  stage(0, 0);
  __syncthreads();
  for (int kt = 0; kt < 8; ++kt) {
    const int buf = kt & 1;
    if (kt + 1 < 8) stage(kt + 1, buf ^ 1);
#pragma unroll
    for (int c = 0; c < 2; ++c) {
      bf16x8 af = sA[buf][c * 4 + quad][w * 16 + l];
#pragma unroll
      for (int s = 0; s < 4; ++s) {
        bf16x8 bfb = sB[buf][c * 4 + quad][s * 16 + l];
        acc[s] = __builtin_amdgcn_mfma_f32_16x16x32_bf16(af, bfb, acc[s], 0, 0, 0);
      }
    }
    __syncthreads();
  }
#pragma unroll
  for (int s = 0; s < 4; ++s) {
    int j = j0 + s * 16 + l;
    float bv = bO[j];
    int n0 = m0 + w * 16 + quad * 4;
#pragma unroll
    for (int r = 0; r < 4; ++r)
      Y[(size_t)(n0 + r) * DMODEL + j] = acc[s][r] + bv + resid[(size_t)(n0 + r) * DMODEL + j];
  }
}

// ---------------------------------------------------------------------------
// Kernel 5: LayerNorm, one wave per row
// ---------------------------------------------------------------------------
__global__ __launch_bounds__(256) void ln_kernel(
    const float* __restrict__ X, const float* __restrict__ gamma,
    const float* __restrict__ beta, float* __restrict__ Y)
{
  const int w = threadIdx.x >> 6, lane = threadIdx.x & 63;
  const int row = blockIdx.x * 4 + w;
  const float* x = X + (size_t)row * DMODEL + lane * 8;
  float4 a = *(const float4*)x;
  float4 b = *(const float4*)(x + 4);

  float s = a.x + a.y + a.z + a.w + b.x + b.y + b.z + b.w;
#pragma unroll
  for (int m = 1; m < 64; m <<= 1) s += __shfl_xor(s, m);
  float mu = s * (1.f / DMODEL);

  float d0 = a.x - mu, d1 = a.y - mu, d2 = a.z - mu, d3 = a.w - mu;
  float d4 = b.x - mu, d5 = b.y - mu, d6 = b.z - mu, d7 = b.w - mu;
  float v = d0*d0 + d1*d1 + d2*d2 + d3*d3 + d4*d4 + d5*d5 + d6*d6 + d7*d7;
#pragma unroll
  for (int m = 1; m < 64; m <<= 1) v += __shfl_xor(v, m);
  float sc = rsqrtf(v * (1.f / DMODEL) + 1e-5f);

  const float* g = gamma + lane * 8;
  const float* be = beta + lane * 8;
  float4 go = *(const float4*)g;
  float4 g1 = *(const float4*)(g + 4);
  float4 bo = *(const float4*)be;
  float4 b1 = *(const float4*)(be + 4);

  float4 y0, y1;
  y0.x = d0 * sc * go.x + bo.x;  y0.y = d1 * sc * go.y + bo.y;
  y0.z = d2 * sc * go.z + bo.z;  y0.w = d3 * sc * go.w + bo.w;
  y1.x = d4 * sc * g1.x + b1.x;  y1.y = d5 * sc * g1.y + b1.y;
  y1.z = d6 * sc * g1.z + b1.z;  y1.w = d7 * sc * g1.w + b1.w;

  float* yp = Y + (size_t)row * DMODEL + lane * 8;
  *(float4*)yp = y0;
  *(float4*)(yp + 4) = y1;
}

// ---------------------------------------------------------------------------
extern "C" void kernel_launch(void* const* d_in, const int* in_sizes, int n_in,
                              void* d_out, int out_size, void* d_ws, size_t ws_size,
                              hipStream_t stream)
{
  const float* Q     = (const float*)d_in[0];
  const float* K     = (const float*)d_in[1];
  const float* V     = (const float*)d_in[2];
  const float* WQ    = (const float*)d_in[3];
  const float* bQ    = (const float*)d_in[4];
  const float* WK    = (const float*)d_in[5];
  const float* bK    = (const float*)d_in[6];
  const float* WV    = (const float*)d_in[7];
  const float* bV    = (const float*)d_in[8];
  const float* WO    = (const float*)d_in[9];
  const float* bO    = (const float*)d_in[10];
  const float* gamma = (const float*)d_in[11];
  const float* beta  = (const float*)d_in[12];

  const size_t MB = 1ull << 20;
  char* ws = (char*)d_ws;
  u16* Qb   = (u16*)(ws + 0 * MB);                  // 4 MB each
  u16* Kb   = (u16*)(ws + 4 * MB);
  u16* Vb   = (u16*)(ws + 8 * MB);
  u16* WQb  = (u16*)(ws + 12 * MB);                 // 0.5 MB each
  u16* WKb  = (u16*)(ws + 12 * MB + 512 * 1024);
  u16* WVb  = (u16*)(ws + 13 * MB);
  u16* WOb  = (u16*)(ws + 13 * MB + 512 * 1024);
  u16* Qs   = (u16*)(ws + 14 * MB);                 // 4 MB each
  u16* Ks   = (u16*)(ws + 18 * MB);
  u16* Vt   = (u16*)(ws + 22 * MB);                 // projected V^T [j][n]
  u16* ctx  = (u16*)(ws + 26 * MB);
  u16* Opart = (u16*)(ws + 30 * MB);                // 16 MB bf16 (dead after combine)
  float* tmp = (float*)(ws + 30 * MB);              // 8 MB, overlays Opart
  float* Lpart = (float*)(ws + 46 * MB);            // 0.5 MB
  float* out = (float*)d_out;

  cvt7_kernel<<<7168, 256, 0, stream>>>(Q, K, V, WQ, WK, WV, WO,
                                        Qb, Kb, Vb, WQb, WKb, WVb, WOb);
  proj3_kernel<<<dim3(32, 8, 3), 256, 0, stream>>>(Qb, Kb, Vb, WQb, WKb, WVb,
                                                   bQ, bK, bV, Qs, Ks, Vt);
  attn_kernel<<<dim3(32, 16), 512, 0, stream>>>(Qs, Ks, Vt, Opart, Lpart);
  combine_kernel<<<1024, 256, 0, stream>>>(Opart, Lpart, ctx);
  gemmo_kernel<<<dim3(64, 8), 256, 0, stream>>>(ctx, WOb, bO, Q, tmp);
  ln_kernel<<<1024, 256, 0, stream>>>(tmp, gamma, beta, out);
}

// Round 16
// 181.359 us; speedup vs baseline: 2.3471x; 1.0099x over previous
//
#include <hip/hip_runtime.h>
#include <cstdint>

#define N_TOK 4096
#define DMODEL 512
#define NHEADS 8
#define HDIM 64

typedef unsigned short u16;
typedef __bf16 bf16x8 __attribute__((ext_vector_type(8)));
typedef float f32x4 __attribute__((ext_vector_type(4)));

union U128 { uint4 u; bf16x8 b; u16 s[8]; };

__device__ __forceinline__ u16 f2bf(float f) {           // RNE
  uint32_t u = __builtin_bit_cast(uint32_t, f);
  u += 0x7FFFu + ((u >> 16) & 1u);
  return (u16)(u >> 16);
}
__device__ __forceinline__ float bf2f(u16 s) {
  uint32_t u = ((uint32_t)s) << 16;
  return __builtin_bit_cast(float, u);
}
__device__ __forceinline__ uint32_t fbit(float f) { return __builtin_bit_cast(uint32_t, f); }

#if __has_builtin(__builtin_amdgcn_exp2f)
#define EXP2(x) __builtin_amdgcn_exp2f(x)
#else
#define EXP2(x) __expf((x) * 0.6931471805599453f)
#endif

// async global->LDS, 16B/lane, dest = wave-uniform base + lane*16
__device__ __forceinline__ void ldg2lds16(const void* g, void* s) {
  __builtin_amdgcn_global_load_lds(
      (const __attribute__((address_space(1))) void*)g,
      (__attribute__((address_space(3))) void*)s, 16, 0, 0);
}

// ---------------------------------------------------------------------------
// Kernel 0: fp32 -> bf16 pre-convert of Q,K,V,WQ,WK,WV,WO.  7168 x 256.
// (r4 lesson: conversion must live OUTSIDE GEMM K-loops.)
// ---------------------------------------------------------------------------
__global__ __launch_bounds__(256) void cvt7_kernel(
    const float* __restrict__ Q, const float* __restrict__ K, const float* __restrict__ V,
    const float* __restrict__ WQ, const float* __restrict__ WK, const float* __restrict__ WV,
    const float* __restrict__ WO,
    u16* __restrict__ Qb, u16* __restrict__ Kb, u16* __restrict__ Vb,
    u16* __restrict__ WQb, u16* __restrict__ WKb, u16* __restrict__ WVb,
    u16* __restrict__ WOb)
{
  int b = blockIdx.x;
  const float* src; u16* dst; int rel;
  if      (b < 2048) { src = Q;  dst = Qb;  rel = b; }
  else if (b < 4096) { src = K;  dst = Kb;  rel = b - 2048; }
  else if (b < 6144) { src = V;  dst = Vb;  rel = b - 4096; }
  else if (b < 6400) { src = WQ; dst = WQb; rel = b - 6144; }
  else if (b < 6656) { src = WK; dst = WKb; rel = b - 6400; }
  else if (b < 6912) { src = WV; dst = WVb; rel = b - 6656; }
  else               { src = WO; dst = WOb; rel = b - 6912; }
  int i = (rel * 256 + threadIdx.x) * 4;
  float4 f = *(const float4*)(src + i);
  ushort4 o;
  o.x = f2bf(f.x); o.y = f2bf(f.y); o.z = f2bf(f.z); o.w = f2bf(f.w);
  *(ushort4*)(dst + i) = o;
}

// ---------------------------------------------------------------------------
// Kernel 1: fused QKV projection, 128x64 tile, m=2, double-buffered LDS,
// pure global_load_lds staging (bf16 in).  V branch writes V^T (Vt[j][n]).
// grid (32, 8, 3), block 256.
// ---------------------------------------------------------------------------
__global__ __launch_bounds__(256) void proj3_kernel(
    const u16* __restrict__ Qb, const u16* __restrict__ Kb, const u16* __restrict__ Vb,
    const u16* __restrict__ WQb, const u16* __restrict__ WKb, const u16* __restrict__ WVb,
    const float* __restrict__ bQ, const float* __restrict__ bK, const float* __restrict__ bV,
    u16* __restrict__ Qs, u16* __restrict__ Ks, u16* __restrict__ Vt)
{
  const int z = blockIdx.z;
  const u16* A      = (z == 0) ? Qb : (z == 1) ? Kb : Vb;
  const u16* W      = (z == 0) ? WQb : (z == 1) ? WKb : WVb;
  const float* bias = (z == 0) ? bQ : (z == 1) ? bK : bV;

  const int m0 = blockIdx.x * 128;
  const int j0 = blockIdx.y * 64;
  const int tid = threadIdx.x;
  const int w = tid >> 6, lane = tid & 63, quad = lane >> 4, l = lane & 15;

  __shared__ bf16x8 sA[2][8][128];  // 32 KB
  __shared__ bf16x8 sB[2][8][64];   // 16 KB

  const f32x4 zero = {0.f, 0.f, 0.f, 0.f};
  f32x4 acc[2][4];
#pragma unroll
  for (int m = 0; m < 2; ++m)
#pragma unroll
    for (int s = 0; s < 4; ++s) acc[m][s] = zero;

  auto stage = [&](int kt, int buf) {
    const int k0 = kt * 64;
#pragma unroll
    for (int i = 0; i < 4; ++i) {
      const int chunk = 2 * w + (i >> 1), half = (i & 1) * 64;
      const u16* ag = A + (size_t)(m0 + half + lane) * DMODEL + k0 + chunk * 8;
      ldg2lds16(ag, (char*)&sA[buf][chunk][half]);
    }
#pragma unroll
    for (int i = 0; i < 2; ++i) {
      const int chunk = 2 * w + i;
      const u16* bg = W + (size_t)(j0 + lane) * DMODEL + k0 + chunk * 8;
      ldg2lds16(bg, (char*)&sB[buf][chunk][0]);
    }
  };

  stage(0, 0);
  __syncthreads();
  for (int kt = 0; kt < 8; ++kt) {
    const int buf = kt & 1;
    if (kt + 1 < 8) stage(kt + 1, buf ^ 1);
#pragma unroll
    for (int c = 0; c < 2; ++c) {
      bf16x8 af0 = sA[buf][c * 4 + quad][w * 32 + l];
      bf16x8 af1 = sA[buf][c * 4 + quad][w * 32 + 16 + l];
#pragma unroll
      for (int s = 0; s < 4; ++s) {
        bf16x8 bfb = sB[buf][c * 4 + quad][s * 16 + l];
        acc[0][s] = __builtin_amdgcn_mfma_f32_16x16x32_bf16(af0, bfb, acc[0][s], 0, 0, 0);
        acc[1][s] = __builtin_amdgcn_mfma_f32_16x16x32_bf16(af1, bfb, acc[1][s], 0, 0, 0);
      }
    }
    __syncthreads();
  }

#pragma unroll
  for (int m = 0; m < 2; ++m)
#pragma unroll
    for (int s = 0; s < 4; ++s) {
      int j = j0 + s * 16 + l;
      float bv = bias[j];
      int n0 = m0 + w * 32 + m * 16 + quad * 4;
      if (z < 2) {
        u16* Y = (z == 0) ? Qs : Ks;
#pragma unroll
        for (int r = 0; r < 4; ++r)
          Y[(size_t)(n0 + r) * DMODEL + j] = f2bf(acc[m][s][r] + bv);
      } else {
        ushort4 pk;
        pk.x = f2bf(acc[m][s][0] + bv); pk.y = f2bf(acc[m][s][1] + bv);
        pk.z = f2bf(acc[m][s][2] + bv); pk.w = f2bf(acc[m][s][3] + bv);
        *(ushort4*)(Vt + (size_t)j * N_TOK + n0) = pk;   // V^T write
      }
    }
}

// ---------------------------------------------------------------------------
// Kernel 2: flash attention (r8/r12 config — the verified local optimum).
// S^T = K.Q^T, fixed-max softmax, split-K x4, double-buffered K/V,
// key-half pbuf (52 KB LDS), XCD-locality swizzle, fully co-resident grid
// (32 = h+8*split, 16 q-tiles) = 512 blocks = 2/CU.
// r11: >512 blocks breaks co-residency -> L2 locality collapses.
// r7/r9: tighter launch_bounds spills accumulators to scratch.
// r13: device-scope fences/atomics in-body slow the main loop 4.7x.
// r15: v_cvt_pk_bf16_f32 packing is slower than shift-pack.
// ---------------------------------------------------------------------------
__global__ __launch_bounds__(512, 4) void attn_kernel(
    const u16* __restrict__ Qs, const u16* __restrict__ Ks,
    const u16* __restrict__ Vt, u16* __restrict__ Opart, float* __restrict__ Lpart)
{
  const int hs = blockIdx.x;                 // h + 8*split
  const int h = hs & 7, split = hs >> 3;
  const int qt = blockIdx.y;
  const int tid = threadIdx.x;
  const int w = tid >> 6, lane = tid & 63, quad = lane >> 4, l = lane & 15;

  __shared__ bf16x8 kch[2][8][64];               // 16 KB  [buf][d-chunk][key]
  __shared__ bf16x8 vch[2][8][64];               // 16 KB  [buf][key-chunk][vd]
  __shared__ __align__(16) u16 pbuf[8][32][40];  // 20 KB  [wave][q][key-half]

  const int wq0 = qt * 256 + w * 32;

  // Q fragments (B-operand), pre-scaled by log2(e)/8
  bf16x8 qf[2][2];
#pragma unroll
  for (int c = 0; c < 2; ++c)
#pragma unroll
    for (int m = 0; m < 2; ++m) {
      U128 u;
      u.u = *(const uint4*)(Qs + (size_t)(wq0 + m * 16 + l) * DMODEL + h * HDIM + c * 32 + quad * 8);
#pragma unroll
      for (int j = 0; j < 8; ++j) u.s[j] = f2bf(bf2f(u.s[j]) * 0.18033688f);
      qf[c][m] = u.b;
    }

  const f32x4 zero = {0.f, 0.f, 0.f, 0.f};
  f32x4 o[2][4];
  float lsum[2] = {0.f, 0.f};
#pragma unroll
  for (int m = 0; m < 2; ++m)
#pragma unroll
    for (int s = 0; s < 4; ++s) o[m][s] = zero;

  auto stage = [&](int it, int buf) {
    const int j0 = split * 1024 + it * 64;
    if (w < 4) {            // waves 0-3 stage K (8 KB)
      const u16* kg = Ks + (size_t)(j0 + lane) * DMODEL + h * HDIM + w * 16;
      ldg2lds16(kg,     (char*)&kch[buf][2 * w][0]);
      ldg2lds16(kg + 8, (char*)&kch[buf][2 * w + 1][0]);
    } else {                // waves 4-7 stage V^T (8 KB)
      const int w2 = w - 4;
      const u16* vg = Vt + (size_t)(h * HDIM + lane) * N_TOK + j0 + w2 * 16;
      ldg2lds16(vg,     (char*)&vch[buf][2 * w2][0]);
      ldg2lds16(vg + 8, (char*)&vch[buf][2 * w2 + 1][0]);
    }
  };

  stage(0, 0);
  __syncthreads();

  for (int it = 0; it < 16; ++it) {
    const int buf = it & 1;
    if (it + 1 < 16) stage(it + 1, buf ^ 1);   // prefetch overlaps compute

#pragma unroll
    for (int kh = 0; kh < 2; ++kh) {           // two 32-key halves
#pragma unroll
      for (int tt = 0; tt < 2; ++tt) {
        const int t = kh * 2 + tt;
        f32x4 sacc[2];
        sacc[0] = zero; sacc[1] = zero;
#pragma unroll
        for (int c = 0; c < 2; ++c) {
          bf16x8 kf = kch[buf][c * 4 + quad][t * 16 + l];
          sacc[0] = __builtin_amdgcn_mfma_f32_16x16x32_bf16(kf, qf[c][0], sacc[0], 0, 0, 0);
          sacc[1] = __builtin_amdgcn_mfma_f32_16x16x32_bf16(kf, qf[c][1], sacc[1], 0, 0, 0);
        }
#pragma unroll
        for (int m = 0; m < 2; ++m) {
          float p0 = EXP2(sacc[m][0]);
          float p1 = EXP2(sacc[m][1]);
          float p2 = EXP2(sacc[m][2]);
          float p3 = EXP2(sacc[m][3]);
          lsum[m] += (p0 + p1) + (p2 + p3);
          uint2 st;
          st.x = (fbit(p0) >> 16) | (fbit(p1) & 0xFFFF0000u);
          st.y = (fbit(p2) >> 16) | (fbit(p3) & 0xFFFF0000u);
          *(uint2*)&pbuf[w][m * 16 + l][tt * 16 + quad * 4] = st;   // per-wave
        }
      }
      // PV for this key half (contraction = 32 keys, quad covers them)
      U128 pf0, pf1;
      pf0.u = *(const uint4*)&pbuf[w][l][quad * 8];
      pf1.u = *(const uint4*)&pbuf[w][16 + l][quad * 8];
#pragma unroll
      for (int s = 0; s < 4; ++s) {
        bf16x8 vf = vch[buf][kh * 4 + quad][s * 16 + l];
        o[0][s] = __builtin_amdgcn_mfma_f32_16x16x32_bf16(pf0.b, vf, o[0][s], 0, 0, 0);
        o[1][s] = __builtin_amdgcn_mfma_f32_16x16x32_bf16(pf1.b, vf, o[1][s], 0, 0, 0);
      }
    }
    __syncthreads();   // publishes next buf's loads; orders buf reuse
  }

#pragma unroll
  for (int m = 0; m < 2; ++m) {
    lsum[m] += __shfl_xor(lsum[m], 16);
    lsum[m] += __shfl_xor(lsum[m], 32);
  }
  if (quad == 0) {
    Lpart[((size_t)split * NHEADS + h) * N_TOK + wq0 + l]      = lsum[0];
    Lpart[((size_t)split * NHEADS + h) * N_TOK + wq0 + 16 + l] = lsum[1];
  }
  // Opart[split][h][q][vd] bf16 (unnormalized)
  u16* Ob = Opart + ((size_t)(split * NHEADS + h) * N_TOK + wq0) * 64;
#pragma unroll
  for (int m = 0; m < 2; ++m)
#pragma unroll
    for (int s = 0; s < 4; ++s)
#pragma unroll
      for (int r = 0; r < 4; ++r)
        Ob[(size_t)(m * 16 + quad * 4 + r) * 64 + s * 16 + l] = f2bf(o[m][s][r]);
}

// ---------------------------------------------------------------------------
// Kernel 3: combine split-K partials (4 splits) -> ctx bf16.  1024 x 256.
// ---------------------------------------------------------------------------
__global__ __launch_bounds__(256) void combine_kernel(
    const u16* __restrict__ Opart, const float* __restrict__ Lpart,
    u16* __restrict__ ctx)
{
  int idx = blockIdx.x * 256 + threadIdx.x;
  int n = idx >> 6;
  int c8 = idx & 63;
  int h = c8 >> 3;
  int vd0 = (c8 & 7) * 8;

  float acc[8] = {0, 0, 0, 0, 0, 0, 0, 0};
  float lsum = 0.f;
#pragma unroll
  for (int s = 0; s < 4; ++s) {
    U128 u;
    u.u = *(const uint4*)(Opart + ((size_t)(s * NHEADS + h) * N_TOK + n) * 64 + vd0);
#pragma unroll
    for (int j = 0; j < 8; ++j) acc[j] += bf2f(u.s[j]);
    lsum += Lpart[((size_t)s * NHEADS + h) * N_TOK + n];
  }
  float inv = 1.f / lsum;
  U128 u;
#pragma unroll
  for (int j = 0; j < 8; ++j) u.s[j] = f2bf(acc[j] * inv);
  *(uint4*)(ctx + (size_t)n * DMODEL + h * HDIM + vd0) = u.u;
}

// ---------------------------------------------------------------------------
// Kernel 4: output projection + bias + residual, 64x64 tile, double-buffered.
// grid (64, 8) = 512 blocks = 2/CU.  (r14: row-complete LN fusion loses —
// WO staging traffic doubles.  Keep LN separate.)
// ---------------------------------------------------------------------------
__global__ __launch_bounds__(256) void gemmo_kernel(
    const u16* __restrict__ ctx, const u16* __restrict__ WOb,
    const float* __restrict__ bO, const float* __restrict__ resid,
    float* __restrict__ Y)
{
  const int m0 = blockIdx.x * 64;
  const int j0 = blockIdx.y * 64;
  const int tid = threadIdx.x;
  const int w = tid >> 6, lane = tid & 63, quad = lane >> 4, l = lane & 15;

  __shared__ bf16x8 sA[2][8][64];  // 16 KB
  __shared__ bf16x8 sB[2][8][64];  // 16 KB

  const f32x4 zero = {0.f, 0.f, 0.f, 0.f};
  f32x4 acc[4];
#pragma unroll
  for (int s = 0; s < 4; ++s) acc[s] = zero;

  auto stage = [&](int kt, int buf) {
    const int k0 = kt * 64;
#pragma unroll
    for (int i = 0; i < 2; ++i) {
      const int chunk = 2 * w + i;
      const u16* ag = ctx + (size_t)(m0 + lane) * DMODEL + k0 + chunk * 8;
      ldg2lds16(ag, (char*)&sA[buf][chunk][0]);
      const u16* bg = WOb + (size_t)(j0 + lane) * DMODEL + k0 + chunk * 8;
      ldg2lds16(bg, (char*)&sB[buf][chunk][0]);
    }
  };

  stage(0, 0);
  __syncthreads();
  for (int kt = 0; kt < 8; ++kt) {
    const int buf = kt & 1;
    if (kt + 1 < 8) stage(kt + 1, buf ^ 1);
#pragma unroll
    for (int c = 0; c < 2; ++c) {
      bf16x8 af = sA[buf][c * 4 + quad][w * 16 + l];
#pragma unroll
      for (int s = 0; s < 4; ++s) {
        bf16x8 bfb = sB[buf][c * 4 + quad][s * 16 + l];
        acc[s] = __builtin_amdgcn_mfma_f32_16x16x32_bf16(af, bfb, acc[s], 0, 0, 0);
      }
    }
    __syncthreads();
  }
#pragma unroll
  for (int s = 0; s < 4; ++s) {
    int j = j0 + s * 16 + l;
    float bv = bO[j];
    int n0 = m0 + w * 16 + quad * 4;
#pragma unroll
    for (int r = 0; r < 4; ++r)
      Y[(size_t)(n0 + r) * DMODEL + j] = acc[s][r] + bv + resid[(size_t)(n0 + r) * DMODEL + j];
  }
}

// ---------------------------------------------------------------------------
// Kernel 5: LayerNorm, one wave per row
// ---------------------------------------------------------------------------
__global__ __launch_bounds__(256) void ln_kernel(
    const float* __restrict__ X, const float* __restrict__ gamma,
    const float* __restrict__ beta, float* __restrict__ Y)
{
  const int w = threadIdx.x >> 6, lane = threadIdx.x & 63;
  const int row = blockIdx.x * 4 + w;
  const float* x = X + (size_t)row * DMODEL + lane * 8;
  float4 a = *(const float4*)x;
  float4 b = *(const float4*)(x + 4);

  float s = a.x + a.y + a.z + a.w + b.x + b.y + b.z + b.w;
#pragma unroll
  for (int m = 1; m < 64; m <<= 1) s += __shfl_xor(s, m);
  float mu = s * (1.f / DMODEL);

  float d0 = a.x - mu, d1 = a.y - mu, d2 = a.z - mu, d3 = a.w - mu;
  float d4 = b.x - mu, d5 = b.y - mu, d6 = b.z - mu, d7 = b.w - mu;
  float v = d0*d0 + d1*d1 + d2*d2 + d3*d3 + d4*d4 + d5*d5 + d6*d6 + d7*d7;
#pragma unroll
  for (int m = 1; m < 64; m <<= 1) v += __shfl_xor(v, m);
  float sc = rsqrtf(v * (1.f / DMODEL) + 1e-5f);

  const float* g = gamma + lane * 8;
  const float* be = beta + lane * 8;
  float4 go = *(const float4*)g;
  float4 g1 = *(const float4*)(g + 4);
  float4 bo = *(const float4*)be;
  float4 b1 = *(const float4*)(be + 4);

  float4 y0, y1;
  y0.x = d0 * sc * go.x + bo.x;  y0.y = d1 * sc * go.y + bo.y;
  y0.z = d2 * sc * go.z + bo.z;  y0.w = d3 * sc * go.w + bo.w;
  y1.x = d4 * sc * g1.x + b1.x;  y1.y = d5 * sc * g1.y + b1.y;
  y1.z = d6 * sc * g1.z + b1.z;  y1.w = d7 * sc * g1.w + b1.w;

  float* yp = Y + (size_t)row * DMODEL + lane * 8;
  *(float4*)yp = y0;
  *(float4*)(yp + 4) = y1;
}

// ---------------------------------------------------------------------------
extern "C" void kernel_launch(void* const* d_in, const int* in_sizes, int n_in,
                              void* d_out, int out_size, void* d_ws, size_t ws_size,
                              hipStream_t stream)
{
  const float* Q     = (const float*)d_in[0];
  const float* K     = (const float*)d_in[1];
  const float* V     = (const float*)d_in[2];
  const float* WQ    = (const float*)d_in[3];
  const float* bQ    = (const float*)d_in[4];
  const float* WK    = (const float*)d_in[5];
  const float* bK    = (const float*)d_in[6];
  const float* WV    = (const float*)d_in[7];
  const float* bV    = (const float*)d_in[8];
  const float* WO    = (const float*)d_in[9];
  const float* bO    = (const float*)d_in[10];
  const float* gamma = (const float*)d_in[11];
  const float* beta  = (const float*)d_in[12];

  const size_t MB = 1ull << 20;
  char* ws = (char*)d_ws;
  u16* Qb   = (u16*)(ws + 0 * MB);                  // 4 MB each
  u16* Kb   = (u16*)(ws + 4 * MB);
  u16* Vb   = (u16*)(ws + 8 * MB);
  u16* WQb  = (u16*)(ws + 12 * MB);                 // 0.5 MB each
  u16* WKb  = (u16*)(ws + 12 * MB + 512 * 1024);
  u16* WVb  = (u16*)(ws + 13 * MB);
  u16* WOb  = (u16*)(ws + 13 * MB + 512 * 1024);
  u16* Qs   = (u16*)(ws + 14 * MB);                 // 4 MB each
  u16* Ks   = (u16*)(ws + 18 * MB);
  u16* Vt   = (u16*)(ws + 22 * MB);                 // projected V^T [j][n]
  u16* ctx  = (u16*)(ws + 26 * MB);
  u16* Opart = (u16*)(ws + 30 * MB);                // 16 MB bf16 (dead after combine)
  float* tmp = (float*)(ws + 30 * MB);              // 8 MB, overlays Opart
  float* Lpart = (float*)(ws + 46 * MB);            // 0.5 MB
  float* out = (float*)d_out;

  cvt7_kernel<<<7168, 256, 0, stream>>>(Q, K, V, WQ, WK, WV, WO,
                                        Qb, Kb, Vb, WQb, WKb, WVb, WOb);
  proj3_kernel<<<dim3(32, 8, 3), 256, 0, stream>>>(Qb, Kb, Vb, WQb, WKb, WVb,
                                                   bQ, bK, bV, Qs, Ks, Vt);
  attn_kernel<<<dim3(32, 16), 512, 0, stream>>>(Qs, Ks, Vt, Opart, Lpart);
  combine_kernel<<<1024, 256, 0, stream>>>(Opart, Lpart, ctx);
  gemmo_kernel<<<dim3(64, 8), 256, 0, stream>>>(ctx, WOb, bO, Q, tmp);
  ln_kernel<<<1024, 256, 0, stream>>>(tmp, gamma, beta, out);
}